// Round 1
// baseline (708.603 us; speedup 1.0000x reference)
//
#include <hip/hip_runtime.h>
#include <hip/hip_bf16.h>

// Geometry
#define HWp 12288       // 96*128
#define Hh  96
#define Ww  128
#define Bb  16

// Workspace float offsets for fake-quantized, transposed weights
#define WQ_C1 0         // [196][96]
#define WQ_F1 18816     // [2][64]
#define WQ_F2 18944     // [64][32]
#define WQ_D  20992     // [128][9]   (natural layout)
#define WQ_P  22144     // [128][80]
#define CORFLO_BYTE_OFF 131072   // bf16 cor_flo [B][128][H][W] starts here

// ---------------------------------------------------------------------------
// Kernel 0: per-tensor symmetric int8 fake-quant (Brevitas-style).
// One block per tensor; block-reduce max|w|, then write quantized weights
// transposed to [c][o] layout for contiguous uniform access in later kernels.
// ---------------------------------------------------------------------------
__global__ __launch_bounds__(256) void quant_weights(
    const float* __restrict__ Wc1, const float* __restrict__ Wf1,
    const float* __restrict__ Wf2, const float* __restrict__ Wd,
    const float* __restrict__ Wp, float* __restrict__ wq)
{
  int t = blockIdx.x;
  const float* src; int n, O, C; float* dst;
  if      (t == 0) { src = Wc1; n = 96*196; O = 96; C = 196; dst = wq + WQ_C1; }
  else if (t == 1) { src = Wf1; n = 64*2;   O = 64; C = 2;   dst = wq + WQ_F1; }
  else if (t == 2) { src = Wf2; n = 32*64;  O = 32; C = 64;  dst = wq + WQ_F2; }
  else if (t == 3) { src = Wd;  n = 1152;   O = 0;  C = 0;   dst = wq + WQ_D;  }
  else             { src = Wp;  n = 80*128; O = 80; C = 128; dst = wq + WQ_P;  }

  __shared__ float red[256];
  float m = 0.f;
  for (int i = threadIdx.x; i < n; i += 256) m = fmaxf(m, fabsf(src[i]));
  red[threadIdx.x] = m;
  __syncthreads();
  for (int s = 128; s > 0; s >>= 1) {
    if (threadIdx.x < s) red[threadIdx.x] = fmaxf(red[threadIdx.x], red[threadIdx.x + s]);
    __syncthreads();
  }
  float scale = fmaxf(red[0], 1e-8f) / 127.0f;

  for (int i = threadIdx.x; i < n; i += 256) {
    float q = rintf(src[i] / scale);           // jnp.round = round-half-even
    q = fminf(fmaxf(q, -127.f), 127.f);
    float v = q * scale;
    if (t == 3) dst[i] = v;                    // depthwise kept natural [c][9]
    else { int o = i / C, c = i - o * C; dst[c * O + o] = v; }
  }
}

// ---------------------------------------------------------------------------
// Stage 1: fused  cor = relu(conv1x1_196->96(corr)),
//                 flo = relu(conv1x1_64->32(relu(conv1x1_2->64(flow))))
// writes cor_flo = concat([cor, flo]) as bf16 NCHW into workspace.
// One thread per pixel. Weights are wave-uniform -> scalar loads.
// ---------------------------------------------------------------------------
__global__ __launch_bounds__(256) void stage1_kernel(
    const float* __restrict__ flow, const float* __restrict__ corr,
    const float* __restrict__ bc1, const float* __restrict__ bf1,
    const float* __restrict__ bf2, const float* __restrict__ wq,
    __hip_bfloat16* __restrict__ cor_flo)
{
  int pix = blockIdx.x * 256 + threadIdx.x;     // 0 .. 196607
  int b = pix / HWp;
  int p = pix - b * HWp;

  // ---- flow path ----
  float x0 = flow[(size_t)(b * 2 + 0) * HWp + p];
  float x1 = flow[(size_t)(b * 2 + 1) * HWp + p];
  const float* wf1 = wq + WQ_F1;                // [2][64]
  float h[64];
#pragma unroll
  for (int o = 0; o < 64; o++)
    h[o] = fmaxf(bf1[o] + x0 * wf1[o] + x1 * wf1[64 + o], 0.f);

  const float* wf2 = wq + WQ_F2;                // [64][32]
  float g[32];
#pragma unroll
  for (int o = 0; o < 32; o++) g[o] = bf2[o];
#pragma unroll
  for (int c = 0; c < 64; c++) {
    float a = h[c];
#pragma unroll
    for (int o = 0; o < 32; o++) g[o] += a * wf2[c * 32 + o];
  }
  {
    __hip_bfloat16* dst = cor_flo + ((size_t)b * 128 + 96) * HWp + p;
#pragma unroll
    for (int o = 0; o < 32; o++)
      dst[(size_t)o * HWp] = __float2bfloat16(fmaxf(g[o], 0.f));
  }

  // ---- corr path: 196 -> 96 ----
  float acc[96];
#pragma unroll
  for (int o = 0; o < 96; o++) acc[o] = bc1[o];
  const float* wc1 = wq + WQ_C1;                // [196][96]
  const float* cp = corr + (size_t)b * 196 * HWp + p;
  for (int c = 0; c < 196; c++) {
    float a = cp[(size_t)c * HWp];
    const float* w = wc1 + c * 96;
#pragma unroll
    for (int o = 0; o < 96; o++) acc[o] += a * w[o];
  }
  __hip_bfloat16* dst = cor_flo + (size_t)b * 128 * HWp + p;
#pragma unroll
  for (int o = 0; o < 96; o++)
    dst[(size_t)o * HWp] = __float2bfloat16(fmaxf(acc[o], 0.f));
}

// ---------------------------------------------------------------------------
// Stage 2: fused depthwise 3x3 (pad=1, no bias) + 128->80 pointwise + ReLU,
// then concat flow into channels 80..81. One thread per pixel, 32x8 tiles.
// ---------------------------------------------------------------------------
__global__ __launch_bounds__(256) void stage2_kernel(
    const __hip_bfloat16* __restrict__ cor_flo, const float* __restrict__ wq,
    const float* __restrict__ bp, const float* __restrict__ flow,
    float* __restrict__ out)
{
  int tx = threadIdx.x & 31, ty = threadIdx.x >> 5;
  int x = blockIdx.x * 32 + tx;
  int y = blockIdx.y * 8 + ty;
  int b = blockIdx.z;

  float acc[80];
#pragma unroll
  for (int o = 0; o < 80; o++) acc[o] = bp[o];

  const float* wd = wq + WQ_D;                  // [128][9]
  const float* wp = wq + WQ_P;                  // [128][80]
  const __hip_bfloat16* base = cor_flo + (size_t)b * 128 * HWp;

  for (int c = 0; c < 128; c++) {
    const __hip_bfloat16* pc = base + (size_t)c * HWp;
    const float* wdc = wd + c * 9;
    float d = 0.f;
#pragma unroll
    for (int dy = -1; dy <= 1; dy++) {
      int yy = y + dy;
      if ((unsigned)yy < (unsigned)Hh) {
#pragma unroll
        for (int dx = -1; dx <= 1; dx++) {
          int xx = x + dx;
          if ((unsigned)xx < (unsigned)Ww)
            d += __bfloat162float(pc[yy * Ww + xx]) * wdc[(dy + 1) * 3 + (dx + 1)];
        }
      }
    }
#pragma unroll
    for (int o = 0; o < 80; o++) acc[o] += d * wp[c * 80 + o];
  }

  float* ob = out + (size_t)b * 82 * HWp + y * Ww + x;
#pragma unroll
  for (int o = 0; o < 80; o++) ob[(size_t)o * HWp] = fmaxf(acc[o], 0.f);
  // concat flow
  ob[(size_t)80 * HWp] = flow[(size_t)(b * 2 + 0) * HWp + y * Ww + x];
  ob[(size_t)81 * HWp] = flow[(size_t)(b * 2 + 1) * HWp + y * Ww + x];
}

// ---------------------------------------------------------------------------
extern "C" void kernel_launch(void* const* d_in, const int* in_sizes, int n_in,
                              void* d_out, int out_size, void* d_ws, size_t ws_size,
                              hipStream_t stream)
{
  const float* flow = (const float*)d_in[0];
  const float* corr = (const float*)d_in[1];
  const float* Wc1  = (const float*)d_in[2];
  const float* bc1  = (const float*)d_in[3];
  const float* Wf1  = (const float*)d_in[4];
  const float* bf1  = (const float*)d_in[5];
  const float* Wf2  = (const float*)d_in[6];
  const float* bf2  = (const float*)d_in[7];
  const float* Wd   = (const float*)d_in[8];
  const float* Wp   = (const float*)d_in[9];
  const float* bp   = (const float*)d_in[10];

  float* wq = (float*)d_ws;
  __hip_bfloat16* cor_flo = (__hip_bfloat16*)((char*)d_ws + CORFLO_BYTE_OFF);
  float* out = (float*)d_out;

  hipLaunchKernelGGL(quant_weights, dim3(5), dim3(256), 0, stream,
                     Wc1, Wf1, Wf2, Wd, Wp, wq);
  hipLaunchKernelGGL(stage1_kernel, dim3(768), dim3(256), 0, stream,
                     flow, corr, bc1, bf1, bf2, wq, cor_flo);
  hipLaunchKernelGGL(stage2_kernel, dim3(4, 12, 16), dim3(256), 0, stream,
                     cor_flo, wq, bp, flow, out);
}

// Round 2
// 360.677 us; speedup vs baseline: 1.9646x; 1.9646x over previous
//
#include <hip/hip_runtime.h>

typedef unsigned short ushort_t;
typedef __attribute__((ext_vector_type(8))) short short8;
typedef __attribute__((ext_vector_type(4))) float f32x4;

#define HWp 12288      // 96*128
#define NB  16

// workspace byte offsets
#define OFF_WFRAG1 0        // bf16 [7 kb][6 mb][64 lane][8 j]  (c1: 96x224)
#define OFF_WFRAG2 43008    // bf16 [4 kb][5 mb][64 lane][8 j]  (pw: 80x128)
#define OFF_WF1T   63488    // f32 [2][64]
#define OFF_WF2T   64000    // f32 [64][32]
#define OFF_WDQ    72192    // f32 [128][9]
#define OFF_CORFLO 131072   // bf16 [16][128][12288]

__device__ __forceinline__ short f2bf(float f) {
  unsigned u = __builtin_bit_cast(unsigned, f);
  u = (u + 0x7FFFu + ((u >> 16) & 1u)) >> 16;   // RNE, matches __float2bfloat16
  return (short)u;
}
__device__ __forceinline__ float bf2f(ushort_t u) {
  return __builtin_bit_cast(float, (unsigned)u << 16);
}
// spread the 16B slots of actc across banks (write side is px-stride-4)
__device__ __forceinline__ int swz(int a16) { return a16 ^ ((a16 >> 2) & 3); }

// ---------------------------------------------------------------------------
// Kernel 0: fake-quant all weights; pack the two GEMM weights into MFMA
// A-fragment order (bf16), transpose the small flow weights, copy dw weights.
// ---------------------------------------------------------------------------
__global__ __launch_bounds__(1024) void quant_pack(
    const float* __restrict__ Wc1, const float* __restrict__ Wf1,
    const float* __restrict__ Wf2, const float* __restrict__ Wd,
    const float* __restrict__ Wp, char* __restrict__ ws)
{
  int t = blockIdx.x;
  const float* src; int n;
  if      (t == 0) { src = Wc1; n = 96*196; }
  else if (t == 1) { src = Wf1; n = 128; }
  else if (t == 2) { src = Wf2; n = 2048; }
  else if (t == 3) { src = Wd;  n = 1152; }
  else             { src = Wp;  n = 10240; }

  __shared__ float red[1024];
  float m = 0.f;
  for (int i = threadIdx.x; i < n; i += 1024) m = fmaxf(m, fabsf(src[i]));
  red[threadIdx.x] = m;
  __syncthreads();
  for (int s = 512; s > 0; s >>= 1) {
    if (threadIdx.x < s) red[threadIdx.x] = fmaxf(red[threadIdx.x], red[threadIdx.x + s]);
    __syncthreads();
  }
  float scale = fmaxf(red[0], 1e-8f) / 127.0f;

  if (t == 0) {
    short* dst = (short*)(ws + OFF_WFRAG1);
    for (int i = threadIdx.x; i < 21504; i += 1024) {
      int j = i & 7, lane = (i >> 3) & 63, rest = i >> 9;
      int mb = rest % 6, kb = rest / 6;
      int ch = mb*16 + (lane & 15);
      int k  = kb*32 + ((lane >> 4) << 3) + j;
      float v = 0.f;
      if (k < 196) {
        float q = rintf(src[ch*196 + k] / scale);
        v = fminf(fmaxf(q, -127.f), 127.f) * scale;
      }
      dst[i] = f2bf(v);
    }
  } else if (t == 4) {
    short* dst = (short*)(ws + OFF_WFRAG2);
    for (int i = threadIdx.x; i < 10240; i += 1024) {
      int j = i & 7, lane = (i >> 3) & 63, rest = i >> 9;
      int mb = rest % 5, kb = rest / 5;
      int ch = mb*16 + (lane & 15);
      int k  = kb*32 + ((lane >> 4) << 3) + j;
      float q = rintf(src[ch*128 + k] / scale);
      dst[i] = f2bf(fminf(fmaxf(q, -127.f), 127.f) * scale);
    }
  } else if (t == 1) {
    float* dst = (float*)(ws + OFF_WF1T);
    for (int i = threadIdx.x; i < 128; i += 1024) {
      int o = i >> 1, c = i & 1;
      float q = rintf(src[i] / scale);
      dst[c*64 + o] = fminf(fmaxf(q, -127.f), 127.f) * scale;
    }
  } else if (t == 2) {
    float* dst = (float*)(ws + OFF_WF2T);
    for (int i = threadIdx.x; i < 2048; i += 1024) {
      int o = i >> 6, c = i & 63;
      float q = rintf(src[i] / scale);
      dst[c*32 + o] = fminf(fmaxf(q, -127.f), 127.f) * scale;
    }
  } else {
    float* dst = (float*)(ws + OFF_WDQ);
    for (int i = threadIdx.x; i < 1152; i += 1024) {
      float q = rintf(src[i] / scale);
      dst[i] = fminf(fmaxf(q, -127.f), 127.f) * scale;
    }
  }
}

// ---------------------------------------------------------------------------
// Stage 1 (MFMA): cor = relu(Wc1q[96x196] @ corr[196 x 64px]) per 64-px tile.
// LDS act layout [28 kgroup][64 px][8 k] bf16 -> aligned b128, ~2-way banks.
// D layout: ch = mb*16 + (lane>>4)*4 + r, px = lane&15 -> coalesced stores.
// ---------------------------------------------------------------------------
__global__ __launch_bounds__(256, 4) void stage1_mfma(
    const float* __restrict__ corr, const float* __restrict__ bc1,
    char* __restrict__ ws)
{
  __shared__ ushort_t s_act[28*64*8];
  const int t = threadIdx.x;
  const int b = blockIdx.x / 192;
  const int pix_base = (blockIdx.x % 192) * 64;

  // stage corr tile -> bf16 LDS (K padded 196 -> 224 with zeros)
  for (int i = t; i < 1792; i += 256) {          // 28 kg * 64 px, 7 iters
    int px = i & 63, kg = i >> 6, k0 = kg << 3;
    const float* src = corr + ((size_t)b*196 + k0)*HWp + pix_base + px;
    short8 v;
    if (kg < 24) {
#pragma unroll
      for (int j = 0; j < 8; j++) v[j] = f2bf(src[(size_t)j*HWp]);
    } else if (kg == 24) {
#pragma unroll
      for (int j = 0; j < 8; j++) v[j] = (j < 4) ? f2bf(src[(size_t)j*HWp]) : (short)0;
    } else {
#pragma unroll
      for (int j = 0; j < 8; j++) v[j] = 0;
    }
    *(short8*)&s_act[(size_t)i*8] = v;
  }
  __syncthreads();

  const int wave = t >> 6, lane = t & 63;
  const int lg = lane >> 4, lr = lane & 15;
  const int pxl = wave*16 + lr;                  // this lane's B-column (pixel)

  f32x4 acc[6];
#pragma unroll
  for (int i = 0; i < 6; i++) acc[i] = f32x4{0.f, 0.f, 0.f, 0.f};

  const short8* wf = (const short8*)(ws + OFF_WFRAG1);
  for (int kb = 0; kb < 7; kb++) {
    short8 aa = *(const short8*)&s_act[((kb*4 + lg)*64 + pxl)*8];
#pragma unroll
    for (int mb = 0; mb < 6; mb++) {
      short8 w = wf[(kb*6 + mb)*64 + lane];
      acc[mb] = __builtin_amdgcn_mfma_f32_16x16x32_bf16(w, aa, acc[mb], 0, 0, 0);
    }
  }

  ushort_t* cf = (ushort_t*)(ws + OFF_CORFLO) + (size_t)b*128*HWp + pix_base + pxl;
#pragma unroll
  for (int mb = 0; mb < 6; mb++)
#pragma unroll
    for (int r = 0; r < 4; r++) {
      int ch = mb*16 + lg*4 + r;
      float v = fmaxf(acc[mb][r] + bc1[ch], 0.f);
      cf[(size_t)ch * HWp] = (ushort_t)f2bf(v);
    }
}

// ---------------------------------------------------------------------------
// Flow path (scalar, cheap): relu(1x1 2->64) -> relu(1x1 64->32),
// writes channels 96..127 of cor_flo as bf16.
// ---------------------------------------------------------------------------
__global__ __launch_bounds__(256) void flow_path(
    const float* __restrict__ flow, const float* __restrict__ bf1,
    const float* __restrict__ bf2, char* __restrict__ ws)
{
  int pix = blockIdx.x * 256 + threadIdx.x;
  int b = pix / HWp, p = pix - b*HWp;
  const float* wf1t = (const float*)(ws + OFF_WF1T);
  const float* wf2t = (const float*)(ws + OFF_WF2T);
  float x0 = flow[(size_t)(b*2 + 0)*HWp + p];
  float x1 = flow[(size_t)(b*2 + 1)*HWp + p];
  float h[64];
#pragma unroll
  for (int o = 0; o < 64; o++)
    h[o] = fmaxf(bf1[o] + x0*wf1t[o] + x1*wf1t[64 + o], 0.f);
  float g[32];
#pragma unroll
  for (int o = 0; o < 32; o++) g[o] = bf2[o];
#pragma unroll
  for (int c = 0; c < 64; c++) {
    float a = h[c];
#pragma unroll
    for (int o = 0; o < 32; o++) g[o] += a * wf2t[c*32 + o];
  }
  ushort_t* dst = (ushort_t*)(ws + OFF_CORFLO) + ((size_t)b*128 + 96)*HWp + p;
#pragma unroll
  for (int o = 0; o < 32; o++)
    dst[(size_t)o*HWp] = (ushort_t)f2bf(fmaxf(g[o], 0.f));
}

// ---------------------------------------------------------------------------
// Stage 2 (MFMA): per 2-row x 128 tile (256 px): for each 32-ch chunk:
//   stage cor_flo rows (y-halo clamped) -> depthwise 3x3 in regs ->
//   pack bf16 actc [kg][256 px][8] (swizzled) -> one MFMA K-step.
// Epilogue: bias+relu store 80 ch + flow concat (ch 80,81).
// ---------------------------------------------------------------------------
__global__ __launch_bounds__(256, 3) void stage2_mfma(
    const float* __restrict__ bp, const float* __restrict__ flow,
    const char* __restrict__ ws, float* __restrict__ out)
{
  __shared__ ushort_t inb[32*4*128];   // 32 KB: [ch][ry 0..3][x]
  __shared__ ushort_t actc[4*256*8];   // 16 KB: [kg][px][j] (swizzled slots)
  const int t = threadIdx.x;
  const int tile = blockIdx.x;         // 0..47
  const int b = blockIdx.y;
  const int y0 = tile * 2;
  const int wave = t >> 6, lane = t & 63;
  const int lg = lane >> 4, lr = lane & 15;
  const int row = lane >> 5, xq = lane & 31, x0 = xq*4;
  const int y = y0 + row;
  const ushort_t* cf = (const ushort_t*)(ws + OFF_CORFLO) + (size_t)b*128*HWp;
  const float* wdq = (const float*)(ws + OFF_WDQ);
  const short8* wfr2 = (const short8*)(ws + OFF_WFRAG2);

  f32x4 acc[4][5];
#pragma unroll
  for (int g = 0; g < 4; g++)
#pragma unroll
    for (int mb = 0; mb < 5; mb++) acc[g][mb] = f32x4{0.f, 0.f, 0.f, 0.f};

  const bool has_up = (y > 0), has_dn = (y < 95);
  const bool has_l = (x0 > 0), has_r = (x0 < 124);

  for (int cb = 0; cb < 4; cb++) {
    // ---- stage 32 channels x 4 rows (y0-1..y0+2 clamped), 16B units ----
    for (int c = t; c < 2048; c += 256) {
      int x16 = c & 15, ry = (c >> 4) & 3, ch = c >> 6;
      int yc = y0 - 1 + ry; yc = yc < 0 ? 0 : (yc > 95 ? 95 : yc);
      const ushort_t* src = cf + (size_t)(cb*32 + ch)*HWp + yc*128 + x16*8;
      *(short8*)&inb[c*8] = *(const short8*)src;
    }
    __syncthreads();   // inb ready; prev MFMA done -> actc writable

    // ---- depthwise 3x3: 8 channels (oct = wave) x 4 px ----
    float vv[4][8];
#pragma unroll
    for (int i = 0; i < 8; i++) {
      int ch = wave*8 + i;
      const float* w = wdq + (size_t)(cb*32 + ch)*9;
      float o0 = 0.f, o1 = 0.f, o2 = 0.f, o3 = 0.f;
      const ushort_t* rp = &inb[(ch*4 + row)*128 + x0];
#pragma unroll
      for (int dy = 0; dy < 3; dy++) {
        if ((dy == 0 && !has_up) || (dy == 2 && !has_dn)) continue;
        const ushort_t* r = rp + dy*128;
        float c0 = bf2f(r[0]), c1 = bf2f(r[1]), c2 = bf2f(r[2]), c3 = bf2f(r[3]);
        float lf = has_l ? bf2f(r[-1]) : 0.f;
        float rt = has_r ? bf2f(r[4]) : 0.f;
        float w0 = w[dy*3], w1 = w[dy*3 + 1], w2 = w[dy*3 + 2];
        o0 += w0*lf + w1*c0 + w2*c1;
        o1 += w0*c0 + w1*c1 + w2*c2;
        o2 += w0*c1 + w1*c2 + w2*c3;
        o3 += w0*c2 + w1*c3 + w2*rt;
      }
      vv[0][i] = o0; vv[1][i] = o1; vv[2][i] = o2; vv[3][i] = o3;
    }
    // pack to bf16 fragments
#pragma unroll
    for (int p = 0; p < 4; p++) {
      short8 pk;
#pragma unroll
      for (int i = 0; i < 8; i++) pk[i] = f2bf(vv[p][i]);
      *(short8*)&actc[swz(wave*256 + row*128 + x0 + p)*8] = pk;
    }
    __syncthreads();   // actc ready

    // ---- MFMA K-step for this chunk ----
    short8 wv[5];
#pragma unroll
    for (int mb = 0; mb < 5; mb++) wv[mb] = wfr2[(cb*5 + mb)*64 + lane];
#pragma unroll
    for (int g = 0; g < 4; g++) {
      int px = wave*64 + g*16 + lr;
      short8 aa = *(const short8*)&actc[swz(lg*256 + px)*8];
#pragma unroll
      for (int mb = 0; mb < 5; mb++)
        acc[g][mb] = __builtin_amdgcn_mfma_f32_16x16x32_bf16(wv[mb], aa, acc[g][mb], 0, 0, 0);
    }
    // no barrier needed here: next stage writes inb only, after the first sync
  }

  // ---- epilogue: bias + relu, then flow concat ----
  const size_t pix0 = (size_t)y0 * 128;
#pragma unroll
  for (int g = 0; g < 4; g++) {
    int px = wave*64 + g*16 + lr;
    float* dst = out + ((size_t)b*82)*HWp + pix0 + px;
#pragma unroll
    for (int mb = 0; mb < 5; mb++)
#pragma unroll
      for (int r = 0; r < 4; r++) {
        int ch = mb*16 + lg*4 + r;
        dst[(size_t)ch*HWp] = fmaxf(acc[g][mb][r] + bp[ch], 0.f);
      }
  }
  {
    size_t p = pix0 + t;
    out[((size_t)b*82 + 80)*HWp + p] = flow[((size_t)b*2 + 0)*HWp + p];
    out[((size_t)b*82 + 81)*HWp + p] = flow[((size_t)b*2 + 1)*HWp + p];
  }
}

// ---------------------------------------------------------------------------
extern "C" void kernel_launch(void* const* d_in, const int* in_sizes, int n_in,
                              void* d_out, int out_size, void* d_ws, size_t ws_size,
                              hipStream_t stream)
{
  const float* flow = (const float*)d_in[0];
  const float* corr = (const float*)d_in[1];
  const float* Wc1  = (const float*)d_in[2];
  const float* bc1  = (const float*)d_in[3];
  const float* Wf1  = (const float*)d_in[4];
  const float* bf1  = (const float*)d_in[5];
  const float* Wf2  = (const float*)d_in[6];
  const float* bf2  = (const float*)d_in[7];
  const float* Wd   = (const float*)d_in[8];
  const float* Wp   = (const float*)d_in[9];
  const float* bp   = (const float*)d_in[10];
  char* ws = (char*)d_ws;
  float* out = (float*)d_out;

  hipLaunchKernelGGL(quant_pack, dim3(5), dim3(1024), 0, stream,
                     Wc1, Wf1, Wf2, Wd, Wp, ws);
  hipLaunchKernelGGL(stage1_mfma, dim3(3072), dim3(256), 0, stream,
                     corr, bc1, ws);
  hipLaunchKernelGGL(flow_path, dim3(768), dim3(256), 0, stream,
                     flow, bf1, bf2, ws);
  hipLaunchKernelGGL(stage2_mfma, dim3(48, 16), dim3(256), 0, stream,
                     bp, flow, ws, out);
}

// Round 3
// 351.139 us; speedup vs baseline: 2.0180x; 1.0272x over previous
//
#include <hip/hip_runtime.h>

typedef unsigned short ushort_t;
typedef __attribute__((ext_vector_type(8))) short short8;
typedef __attribute__((ext_vector_type(4))) float f32x4;

#define HWp 12288      // 96*128
#define NB  16

// workspace byte offsets
#define OFF_WFRAG1 0        // bf16 [7 kb][6 mb][64 lane][8 j]  (c1: 96x224)
#define OFF_WFRAG2 43008    // bf16 [4 kb][5 mb][64 lane][8 j]  (pw: 80x128)
#define OFF_WF1T   63488    // f32 [2][64]
#define OFF_WF2T   64000    // f32 [64][32]
#define OFF_WDQ    72192    // f32 [128][9]
#define OFF_CORFLO 131072   // bf16 [16][128][12288]

__device__ __forceinline__ short f2bf(float f) {
  unsigned u = __builtin_bit_cast(unsigned, f);
  u = (u + 0x7FFFu + ((u >> 16) & 1u)) >> 16;   // RNE
  return (short)u;
}
__device__ __forceinline__ float bf2f(ushort_t u) {
  return __builtin_bit_cast(float, (unsigned)u << 16);
}
__device__ __forceinline__ int swz(int a16) { return a16 ^ ((a16 >> 2) & 3); }

__device__ __forceinline__ void gload_lds16(const void* g, void* l) {
  __builtin_amdgcn_global_load_lds(
      (const __attribute__((address_space(1))) unsigned*)g,
      (__attribute__((address_space(3))) unsigned*)l, 16, 0, 0);
}

// ---------------------------------------------------------------------------
// Kernel 0: fake-quant all weights; pack GEMM weights into MFMA A-fragment
// order (bf16); transpose flow weights; copy dw weights.
// ---------------------------------------------------------------------------
__global__ __launch_bounds__(1024) void quant_pack(
    const float* __restrict__ Wc1, const float* __restrict__ Wf1,
    const float* __restrict__ Wf2, const float* __restrict__ Wd,
    const float* __restrict__ Wp, char* __restrict__ ws)
{
  int t = blockIdx.x;
  const float* src; int n;
  if      (t == 0) { src = Wc1; n = 96*196; }
  else if (t == 1) { src = Wf1; n = 128; }
  else if (t == 2) { src = Wf2; n = 2048; }
  else if (t == 3) { src = Wd;  n = 1152; }
  else             { src = Wp;  n = 10240; }

  __shared__ float red[1024];
  float m = 0.f;
  for (int i = threadIdx.x; i < n; i += 1024) m = fmaxf(m, fabsf(src[i]));
  red[threadIdx.x] = m;
  __syncthreads();
  for (int s = 512; s > 0; s >>= 1) {
    if (threadIdx.x < s) red[threadIdx.x] = fmaxf(red[threadIdx.x], red[threadIdx.x + s]);
    __syncthreads();
  }
  float scale = fmaxf(red[0], 1e-8f) / 127.0f;

  if (t == 0) {
    short* dst = (short*)(ws + OFF_WFRAG1);
    for (int i = threadIdx.x; i < 21504; i += 1024) {
      int j = i & 7, lane = (i >> 3) & 63, rest = i >> 9;
      int mb = rest % 6, kb = rest / 6;
      int ch = mb*16 + (lane & 15);
      int k  = kb*32 + ((lane >> 4) << 3) + j;
      float v = 0.f;
      if (k < 196) {
        float q = rintf(src[ch*196 + k] / scale);
        v = fminf(fmaxf(q, -127.f), 127.f) * scale;
      }
      dst[i] = f2bf(v);
    }
  } else if (t == 4) {
    short* dst = (short*)(ws + OFF_WFRAG2);
    for (int i = threadIdx.x; i < 10240; i += 1024) {
      int j = i & 7, lane = (i >> 3) & 63, rest = i >> 9;
      int mb = rest % 5, kb = rest / 5;
      int ch = mb*16 + (lane & 15);
      int k  = kb*32 + ((lane >> 4) << 3) + j;
      float q = rintf(src[ch*128 + k] / scale);
      dst[i] = f2bf(fminf(fmaxf(q, -127.f), 127.f) * scale);
    }
  } else if (t == 1) {
    float* dst = (float*)(ws + OFF_WF1T);
    for (int i = threadIdx.x; i < 128; i += 1024) {
      int o = i >> 1, c = i & 1;
      float q = rintf(src[i] / scale);
      dst[c*64 + o] = fminf(fmaxf(q, -127.f), 127.f) * scale;
    }
  } else if (t == 2) {
    float* dst = (float*)(ws + OFF_WF2T);
    for (int i = threadIdx.x; i < 2048; i += 1024) {
      int o = i >> 6, c = i & 63;
      float q = rintf(src[i] / scale);
      dst[c*32 + o] = fminf(fmaxf(q, -127.f), 127.f) * scale;
    }
  } else {
    float* dst = (float*)(ws + OFF_WDQ);
    for (int i = threadIdx.x; i < 1152; i += 1024) {
      float q = rintf(src[i] / scale);
      dst[i] = fminf(fmaxf(q, -127.f), 127.f) * scale;
    }
  }
}

// ---------------------------------------------------------------------------
// Stage 1 (MFMA, no LDS, no barriers): cor = relu(Wc1q @ corr) per 128-px
// block; each wave owns 32 px (2 B-fragments). B-fragments loaded DIRECTLY
// from global into registers (lane: px=lane&15, k=kb*32+(lane>>4)*8+j ->
// 4x64B coalesced segments per load inst), converted to bf16, MFMA'd.
// Weights (43 KB, L2-hot) read per-kb as 16B/lane fragments.
// ---------------------------------------------------------------------------
__global__ __launch_bounds__(256, 3) void stage1_mfma(
    const float* __restrict__ corr, const float* __restrict__ bc1,
    char* __restrict__ ws)
{
  const int t = threadIdx.x;
  const int wave = t >> 6, lane = t & 63;
  const int lg = (lane >> 4) & 3, lr = lane & 15;
  const int b = blockIdx.x / 96;
  const int px0 = (blockIdx.x % 96) * 128 + wave * 32;

  f32x4 acc[2][6];
#pragma unroll
  for (int f = 0; f < 2; f++)
#pragma unroll
    for (int mb = 0; mb < 6; mb++) acc[f][mb] = f32x4{0.f, 0.f, 0.f, 0.f};

  const short8* wf = (const short8*)(ws + OFF_WFRAG1);
  const float* cbase = corr + (size_t)b * 196 * HWp;

#pragma unroll
  for (int kb = 0; kb < 7; kb++) {
    short8 aa[2];
#pragma unroll
    for (int f = 0; f < 2; f++) {
      const float* src = cbase + (size_t)(kb*32 + lg*8) * HWp + px0 + f*16 + lr;
#pragma unroll
      for (int j = 0; j < 8; j++) {
        int k = kb*32 + lg*8 + j;
        float v = (k < 196) ? src[(size_t)j * HWp] : 0.f;
        aa[f][j] = f2bf(v);
      }
    }
#pragma unroll
    for (int mb = 0; mb < 6; mb++) {
      short8 w = wf[(kb*6 + mb)*64 + lane];
      acc[0][mb] = __builtin_amdgcn_mfma_f32_16x16x32_bf16(w, aa[0], acc[0][mb], 0, 0, 0);
      acc[1][mb] = __builtin_amdgcn_mfma_f32_16x16x32_bf16(w, aa[1], acc[1][mb], 0, 0, 0);
    }
  }

  ushort_t* cf = (ushort_t*)(ws + OFF_CORFLO) + (size_t)b*128*HWp;
#pragma unroll
  for (int f = 0; f < 2; f++) {
    int px = px0 + f*16 + lr;
#pragma unroll
    for (int mb = 0; mb < 6; mb++)
#pragma unroll
      for (int r = 0; r < 4; r++) {
        int ch = mb*16 + lg*4 + r;
        cf[(size_t)ch*HWp + px] = (ushort_t)f2bf(fmaxf(acc[f][mb][r] + bc1[ch], 0.f));
      }
  }
}

// ---------------------------------------------------------------------------
// Flow path (scalar, ~6 us): relu(1x1 2->64) -> relu(1x1 64->32),
// writes channels 96..127 of cor_flo as bf16.
// ---------------------------------------------------------------------------
__global__ __launch_bounds__(256) void flow_path(
    const float* __restrict__ flow, const float* __restrict__ bf1,
    const float* __restrict__ bf2, char* __restrict__ ws)
{
  int pix = blockIdx.x * 256 + threadIdx.x;
  int b = pix / HWp, p = pix - b*HWp;
  const float* wf1t = (const float*)(ws + OFF_WF1T);
  const float* wf2t = (const float*)(ws + OFF_WF2T);
  float x0 = flow[(size_t)(b*2 + 0)*HWp + p];
  float x1 = flow[(size_t)(b*2 + 1)*HWp + p];
  float h[64];
#pragma unroll
  for (int o = 0; o < 64; o++)
    h[o] = fmaxf(bf1[o] + x0*wf1t[o] + x1*wf1t[64 + o], 0.f);
  float g[32];
#pragma unroll
  for (int o = 0; o < 32; o++) g[o] = bf2[o];
#pragma unroll
  for (int c = 0; c < 64; c++) {
    float a = h[c];
#pragma unroll
    for (int o = 0; o < 32; o++) g[o] += a * wf2t[c*32 + o];
  }
  ushort_t* dst = (ushort_t*)(ws + OFF_CORFLO) + ((size_t)b*128 + 96)*HWp + p;
#pragma unroll
  for (int o = 0; o < 32; o++)
    dst[(size_t)o*HWp] = (ushort_t)f2bf(fmaxf(g[o], 0.f));
}

// ---------------------------------------------------------------------------
// Stage 2 (MFMA): per 2-row x 128 tile: for each 32-ch chunk:
//   global_load_lds stage (async DMA, no VGPR roundtrip) -> depthwise 3x3
//   in regs -> pack bf16 actc (swizzled) -> one MFMA K-step.
// Pipeline: chunk cb+1's staging is issued BEFORE chunk cb's MFMA so HBM
// latency hides under the matrix pipe (T3-lite 2-phase schedule).
// ---------------------------------------------------------------------------
__global__ __launch_bounds__(256, 3) void stage2_mfma(
    const float* __restrict__ bp, const float* __restrict__ flow,
    const char* __restrict__ ws, float* __restrict__ out)
{
  __shared__ ushort_t inb[32*4*128];   // 32 KB: [ch][ry 0..3][x]
  __shared__ ushort_t actc[4*256*8];   // 16 KB: [kg][px][j] (swizzled slots)
  const int t = threadIdx.x;
  const int tile = blockIdx.x;         // 0..47
  const int b = blockIdx.y;
  const int y0 = tile * 2;
  const int wave = t >> 6, lane = t & 63;
  const int lg = lane >> 4, lr = lane & 15;
  const int row = lane >> 5, xq = lane & 31, x0 = xq*4;
  const int y = y0 + row;
  const ushort_t* cf = (const ushort_t*)(ws + OFF_CORFLO) + (size_t)b*128*HWp;
  const float* wdq = (const float*)(ws + OFF_WDQ);
  const short8* wfr2 = (const short8*)(ws + OFF_WFRAG2);

  f32x4 acc[4][5];
#pragma unroll
  for (int g = 0; g < 4; g++)
#pragma unroll
    for (int mb = 0; mb < 5; mb++) acc[g][mb] = f32x4{0.f, 0.f, 0.f, 0.f};

  const bool has_up = (y > 0), has_dn = (y < 95);
  const bool has_l = (x0 > 0), has_r = (x0 < 124);

  // issue chunk-0 staging
#pragma unroll
  for (int i = 0; i < 8; i++) {
    int u = i*256 + t;
    int x16 = u & 15, ry = (u >> 4) & 3, ch = u >> 6;
    int yc = y0 - 1 + ry; yc = yc < 0 ? 0 : (yc > 95 ? 95 : yc);
    gload_lds16(cf + (size_t)ch*HWp + yc*128 + x16*8, &inb[u*8]);
  }

  for (int cb = 0; cb < 4; cb++) {
    __syncthreads();   // drains vmcnt -> inb ready; prev MFMA done -> actc writable

    // ---- depthwise 3x3: 8 channels (oct = wave) x 4 px ----
    float vv[4][8];
#pragma unroll
    for (int i = 0; i < 8; i++) {
      int ch = wave*8 + i;
      const float* w = wdq + (size_t)(cb*32 + ch)*9;
      float o0 = 0.f, o1 = 0.f, o2 = 0.f, o3 = 0.f;
      const ushort_t* rp = &inb[(ch*4 + row)*128 + x0];
#pragma unroll
      for (int dy = 0; dy < 3; dy++) {
        if ((dy == 0 && !has_up) || (dy == 2 && !has_dn)) continue;
        const ushort_t* r = rp + dy*128;
        float c0 = bf2f(r[0]), c1 = bf2f(r[1]), c2 = bf2f(r[2]), c3 = bf2f(r[3]);
        float lf = has_l ? bf2f(r[-1]) : 0.f;
        float rt = has_r ? bf2f(r[4]) : 0.f;
        float w0 = w[dy*3], w1 = w[dy*3 + 1], w2 = w[dy*3 + 2];
        o0 += w0*lf + w1*c0 + w2*c1;
        o1 += w0*c0 + w1*c1 + w2*c2;
        o2 += w0*c1 + w1*c2 + w2*c3;
        o3 += w0*c2 + w1*c3 + w2*rt;
      }
      vv[0][i] = o0; vv[1][i] = o1; vv[2][i] = o2; vv[3][i] = o3;
    }
#pragma unroll
    for (int p = 0; p < 4; p++) {
      short8 pk;
#pragma unroll
      for (int i = 0; i < 8; i++) pk[i] = f2bf(vv[p][i]);
      *(short8*)&actc[swz(wave*256 + row*128 + x0 + p)*8] = pk;
    }
    __syncthreads();   // actc ready AND all inb reads done

    // ---- prefetch next chunk's staging (overlaps with MFMA below) ----
    if (cb < 3) {
#pragma unroll
      for (int i = 0; i < 8; i++) {
        int u = i*256 + t;
        int x16 = u & 15, ry = (u >> 4) & 3, ch = u >> 6;
        int yc = y0 - 1 + ry; yc = yc < 0 ? 0 : (yc > 95 ? 95 : yc);
        gload_lds16(cf + (size_t)((cb+1)*32 + ch)*HWp + yc*128 + x16*8, &inb[u*8]);
      }
    }

    // ---- MFMA K-step for this chunk ----
    short8 wv[5];
#pragma unroll
    for (int mb = 0; mb < 5; mb++) wv[mb] = wfr2[(cb*5 + mb)*64 + lane];
#pragma unroll
    for (int g = 0; g < 4; g++) {
      int px = wave*64 + g*16 + lr;
      short8 aa = *(const short8*)&actc[swz(lg*256 + px)*8];
#pragma unroll
      for (int mb = 0; mb < 5; mb++)
        acc[g][mb] = __builtin_amdgcn_mfma_f32_16x16x32_bf16(wv[mb], aa, acc[g][mb], 0, 0, 0);
    }
  }

  // ---- epilogue: bias + relu, then flow concat ----
  const size_t pix0 = (size_t)y0 * 128;
#pragma unroll
  for (int g = 0; g < 4; g++) {
    int px = wave*64 + g*16 + lr;
    float* dst = out + ((size_t)b*82)*HWp + pix0 + px;
#pragma unroll
    for (int mb = 0; mb < 5; mb++)
#pragma unroll
      for (int r = 0; r < 4; r++) {
        int ch = mb*16 + lg*4 + r;
        dst[(size_t)ch*HWp] = fmaxf(acc[g][mb][r] + bp[ch], 0.f);
      }
  }
  {
    size_t p = pix0 + t;
    out[((size_t)b*82 + 80)*HWp + p] = flow[((size_t)b*2 + 0)*HWp + p];
    out[((size_t)b*82 + 81)*HWp + p] = flow[((size_t)b*2 + 1)*HWp + p];
  }
}

// ---------------------------------------------------------------------------
extern "C" void kernel_launch(void* const* d_in, const int* in_sizes, int n_in,
                              void* d_out, int out_size, void* d_ws, size_t ws_size,
                              hipStream_t stream)
{
  const float* flow = (const float*)d_in[0];
  const float* corr = (const float*)d_in[1];
  const float* Wc1  = (const float*)d_in[2];
  const float* bc1  = (const float*)d_in[3];
  const float* Wf1  = (const float*)d_in[4];
  const float* bf1  = (const float*)d_in[5];
  const float* Wf2  = (const float*)d_in[6];
  const float* bf2  = (const float*)d_in[7];
  const float* Wd   = (const float*)d_in[8];
  const float* Wp   = (const float*)d_in[9];
  const float* bp   = (const float*)d_in[10];
  char* ws = (char*)d_ws;
  float* out = (float*)d_out;

  hipLaunchKernelGGL(quant_pack, dim3(5), dim3(1024), 0, stream,
                     Wc1, Wf1, Wf2, Wd, Wp, ws);
  hipLaunchKernelGGL(stage1_mfma, dim3(1536), dim3(256), 0, stream,
                     corr, bc1, ws);
  hipLaunchKernelGGL(flow_path, dim3(768), dim3(256), 0, stream,
                     flow, bf1, bf2, ws);
  hipLaunchKernelGGL(stage2_mfma, dim3(48, 16), dim3(256), 0, stream,
                     bp, flow, ws, out);
}